// Round 1
// baseline (199.701 us; speedup 1.0000x reference)
//
#include <hip/hip_runtime.h>
#include <hip/hip_bf16.h>

// ---------- types ----------
typedef unsigned short ushortT;
typedef __bf16 bf16x8 __attribute__((ext_vector_type(8)));
typedef float f32x4 __attribute__((ext_vector_type(4)));
typedef ushortT ush8 __attribute__((ext_vector_type(8)));
typedef ushortT ush4 __attribute__((ext_vector_type(4)));

#define MFMA16(a, b, c) __builtin_amdgcn_mfma_f32_16x16x32_bf16((a), (b), (c), 0, 0, 0)

__device__ __forceinline__ ushortT f2b(float f) {
  __hip_bfloat16 h = __float2bfloat16(f);
  return __builtin_bit_cast(ushortT, h);
}
__device__ __forceinline__ float b2f(ushortT u) {
  __hip_bfloat16 h = __builtin_bit_cast(__hip_bfloat16, u);
  return __bfloat162float(h);
}

// ---------- problem dims ----------
// B=4, S=512, D=256, ROWS = B*S = 2048
#define ACT_E 524288   // 2048*256 elements
#define WD_E  65536    // 256*256

// ---------- ws layout (bytes) ----------
#define OFF_ACT16   0u          // 3 * ACT_E * 2 = 3145728
#define OFF_ACTT16  3145728u    // 3 * ACT_E * 2
#define OFF_W16T    6291456u    // 9 * WD_E * 2 = 1179648
#define OFF_PROJ16  7471104u    // 5 * ACT_E * 2 = 5242880
#define OFF_P16     12713984u   // 4 * 1048576 * 2 = 8388608
#define OFF_VC16    21102592u   // ACT_E*2
#define OFF_AC16    22151168u
#define OFF_PVV32   23199744u   // ACT_E*4
#define OFF_PVA32   25296896u
#define OFF_CFV16   27394048u
#define OFF_CFA16   28442624u
#define OFF_M32     29491200u   // ACT_E*4
#define OFF_BIL16   31588352u   // 16777216*2 = 33554432

// =====================================================================
// 1) convert img/audio/common fp32 -> bf16 (same layout)
// grid 384 x 256
__global__ void k_cvt_acts(const float* __restrict__ img, const float* __restrict__ aud,
                           const float* __restrict__ com, ushortT* __restrict__ dst) {
  int i4 = blockIdx.x * 256 + threadIdx.x;
#pragma unroll
  for (int q = 0; q < 4; q++) {
    int idx4 = i4 + q * 98304;       // 0..393215
    int flat = idx4 * 4;
    const float* src;
    int off;
    if (flat < 524288)        { src = img; off = flat; }
    else if (flat < 1048576)  { src = aud; off = flat - 524288; }
    else                      { src = com; off = flat - 1048576; }
    float4 v = *(const float4*)(src + off);
    ush4 u = { f2b(v.x), f2b(v.y), f2b(v.z), f2b(v.w) };
    *(ush4*)(dst + idx4 * 4) = u;
  }
}

// 2) convert bil_w fp32 -> bf16, grid 2048 x 256
__global__ void k_cvt_bil(const float* __restrict__ bil, ushortT* __restrict__ dst) {
  int i4 = blockIdx.x * 256 + threadIdx.x;  // 0..524287
#pragma unroll
  for (int q = 0; q < 8; q++) {
    int idx4 = i4 + q * 524288;             // 0..4194303
    float4 v = *(const float4*)(bil + idx4 * 4);
    ush4 u = { f2b(v.x), f2b(v.y), f2b(v.z), f2b(v.w) };
    *(ush4*)(dst + idx4 * 4) = u;
  }
}

// 3) transpose+convert: activations per-batch [512][256]->[256][512] and
//    weights [256k][256n]->[256n][256k].  grid 528 x 256
__global__ void k_transpose(const float* __restrict__ img, const float* __restrict__ aud,
                            const float* __restrict__ com,
                            const float* w0, const float* w1, const float* w2,
                            const float* w3, const float* w4, const float* w5,
                            const float* w6, const float* w7, const float* w8,
                            ushortT* __restrict__ actT, ushortT* __restrict__ wT) {
  __shared__ ushortT tl[64][72];
  int tid = threadIdx.x;
  int bx = blockIdx.x;
  const float* src;
  ushortT* dst;
  int R, C, r0, c0;
  if (bx < 384) {
    int inst = bx >> 5, tile = bx & 31;
    int act = inst >> 2, bb = inst & 3;
    src = (act == 0 ? img : (act == 1 ? aud : com)) + bb * 131072;
    dst = actT + act * 524288 + bb * 131072;
    R = 512; C = 256;
    r0 = (tile >> 2) * 64; c0 = (tile & 3) * 64;
  } else {
    int bw = bx - 384;
    int w = bw >> 4, tile = bw & 15;
    const float* s;
    switch (w) {
      case 0: s = w0; break; case 1: s = w1; break; case 2: s = w2; break;
      case 3: s = w3; break; case 4: s = w4; break; case 5: s = w5; break;
      case 6: s = w6; break; case 7: s = w7; break; default: s = w8; break;
    }
    src = s;
    dst = wT + w * 65536;
    R = 256; C = 256;
    r0 = (tile >> 2) * 64; c0 = (tile & 3) * 64;
  }
#pragma unroll
  for (int q = 0; q < 4; q++) {
    int rr = q * 16 + (tid >> 4);
    int cs = (tid & 15) * 4;
    float4 v = *(const float4*)(src + (r0 + rr) * C + c0 + cs);
    tl[rr][cs + 0] = f2b(v.x);
    tl[rr][cs + 1] = f2b(v.y);
    tl[rr][cs + 2] = f2b(v.z);
    tl[rr][cs + 3] = f2b(v.w);
  }
  __syncthreads();
#pragma unroll
  for (int q = 0; q < 4; q++) {
    int cc = q * 16 + (tid >> 4);
    int rs = (tid & 15) * 4;
    ush4 u = { tl[rs + 0][cc], tl[rs + 1][cc], tl[rs + 2][cc], tl[rs + 3][cc] };
    *(ush4*)(dst + (c0 + cc) * R + r0 + rs) = u;
  }
}

// =====================================================================
// 4) five input linears: proj = X @ W + b  (bf16 out)
// grid 320 x 512 : op = bx>>6, sblk = bx&63 (BM=32, N=256, K=256)
__global__ __launch_bounds__(512) void k_linear5(
    const ushortT* __restrict__ act16, const ushortT* __restrict__ wT,
    const float* __restrict__ b0, const float* __restrict__ b1,
    const float* __restrict__ b2, const float* __restrict__ b3,
    const float* __restrict__ b4, ushortT* __restrict__ proj16) {
  __shared__ ushortT Al[4][32][8];
  __shared__ ushortT Bl[4][256][8];
  const int tid = threadIdx.x, l = tid & 63, w = tid >> 6;
  const int bx = blockIdx.x;
  const int op = bx >> 6, sblk = bx & 63;
  const int s0 = sblk * 32;
  const int xsel = (op == 4) ? 2 : (op & 1);
  const ushortT* X = act16 + xsel * ACT_E;
  const ushortT* W = wT + op * WD_E;
  const float* bias = op == 0 ? b0 : op == 1 ? b1 : op == 2 ? b2 : op == 3 ? b3 : b4;
  ushortT* out = proj16 + op * ACT_E;

  f32x4 acc[2][2] = {};
  ush8 ra, rb[2];
  int a_row = tid >> 2, a_seg = tid & 3;

  auto sload = [&](int k0) {
    if (tid < 128) ra = *(const ush8*)(X + (s0 + a_row) * 256 + k0 + a_seg * 8);
#pragma unroll
    for (int q = 0; q < 2; q++) {
      int slot = tid + q * 512;
      rb[q] = *(const ush8*)(W + (slot >> 2) * 256 + k0 + (slot & 3) * 8);
    }
  };
  auto swrite = [&]() {
    if (tid < 128) *(ush8*)(&Al[a_seg][a_row][0]) = ra;
#pragma unroll
    for (int q = 0; q < 2; q++) {
      int slot = tid + q * 512;
      *(ush8*)(&Bl[slot & 3][slot >> 2][0]) = rb[q];
    }
  };

  sload(0); swrite(); __syncthreads();
  for (int s = 0; s < 8; s++) {
    if (s < 7) sload((s + 1) * 32);
    int ks = l >> 4;
    bf16x8 a[2], bb[2];
#pragma unroll
    for (int m = 0; m < 2; m++) a[m] = *(const bf16x8*)(&Al[ks][m * 16 + (l & 15)][0]);
#pragma unroll
    for (int n = 0; n < 2; n++) bb[n] = *(const bf16x8*)(&Bl[ks][w * 32 + n * 16 + (l & 15)][0]);
#pragma unroll
    for (int m = 0; m < 2; m++)
#pragma unroll
      for (int n = 0; n < 2; n++) acc[m][n] = MFMA16(a[m], bb[n], acc[m][n]);
    if (s == 7) break;
    __syncthreads();
    swrite();
    __syncthreads();
  }
#pragma unroll
  for (int m = 0; m < 2; m++)
#pragma unroll
    for (int n = 0; n < 2; n++)
#pragma unroll
      for (int r = 0; r < 4; r++) {
        int row = s0 + m * 16 + (l >> 4) * 4 + r;
        int col = w * 32 + n * 16 + (l & 15);
        out[row * 256 + col] = f2b(acc[m][n][r] + bias[col]);
      }
}

// =====================================================================
// 5) attention: P = softmax(Q K^T) * (1/16), bf16 out.
// grid 256 x 512 : p=bx>>6, b=(bx>>4)&3, sblk=bx&15 (32 q-rows per block)
__global__ __launch_bounds__(512) void k_attn(const ushortT* __restrict__ proj16,
                                              ushortT* __restrict__ P16) {
  __shared__ ushortT Ql[8][4][32][8];
  __shared__ ushortT Kl[4][512][8];
  __shared__ float red[32][8];
  const int tid = threadIdx.x, l = tid & 63, w = tid >> 6;
  const int bx = blockIdx.x;
  const int p = bx >> 6, b = (bx >> 4) & 3, sblk = bx & 15;
  const int s0 = sblk * 32;
  const int qsel = (p < 2) ? 0 : 1;
  const int ksel = (p == 0) ? 2 : (p == 2) ? 3 : 4;
  const ushortT* Q = proj16 + qsel * ACT_E + b * 131072;
  const ushortT* K = proj16 + ksel * ACT_E + b * 131072;
  ushortT* P = P16 + p * 1048576 + b * 262144;

  // stage Q fully (32x256)
#pragma unroll
  for (int q = 0; q < 2; q++) {
    int slot = tid + q * 512;
    int row = slot >> 5, seg = slot & 31;
    ush8 v = *(const ush8*)(Q + (s0 + row) * 256 + seg * 8);
    *(ush8*)(&Ql[seg >> 2][seg & 3][row][0]) = v;
  }

  f32x4 acc[2][4] = {};
  ush8 rk[4];
  auto kload = [&](int d0) {
#pragma unroll
    for (int q = 0; q < 4; q++) {
      int slot = tid + q * 512;
      rk[q] = *(const ush8*)(K + (slot >> 2) * 256 + d0 + (slot & 3) * 8);
    }
  };
  auto kwrite = [&]() {
#pragma unroll
    for (int q = 0; q < 4; q++) {
      int slot = tid + q * 512;
      *(ush8*)(&Kl[slot & 3][slot >> 2][0]) = rk[q];
    }
  };

  kload(0); kwrite(); __syncthreads();
  for (int s = 0; s < 8; s++) {
    if (s < 7) kload((s + 1) * 32);
    int ks = l >> 4;
    bf16x8 a[2], bb[4];
#pragma unroll
    for (int m = 0; m < 2; m++) a[m] = *(const bf16x8*)(&Ql[s][ks][m * 16 + (l & 15)][0]);
#pragma unroll
    for (int n = 0; n < 4; n++) bb[n] = *(const bf16x8*)(&Kl[ks][w * 64 + n * 16 + (l & 15)][0]);
#pragma unroll
    for (int m = 0; m < 2; m++)
#pragma unroll
      for (int n = 0; n < 4; n++) acc[m][n] = MFMA16(a[m], bb[n], acc[m][n]);
    if (s == 7) break;
    __syncthreads();
    kwrite();
    __syncthreads();
  }

  // ---- softmax over t (512) ----
  float gmax[2][4];
#pragma unroll
  for (int m = 0; m < 2; m++)
#pragma unroll
    for (int r = 0; r < 4; r++) {
      float v = fmaxf(fmaxf(acc[m][0][r], acc[m][1][r]), fmaxf(acc[m][2][r], acc[m][3][r]));
#pragma unroll
      for (int off = 1; off < 16; off <<= 1) v = fmaxf(v, __shfl_xor(v, off, 16));
      if ((l & 15) == 0) red[m * 16 + (l >> 4) * 4 + r][w] = v;
    }
  __syncthreads();
#pragma unroll
  for (int m = 0; m < 2; m++)
#pragma unroll
    for (int r = 0; r < 4; r++) {
      int sr = m * 16 + (l >> 4) * 4 + r;
      float g = red[sr][0];
#pragma unroll
      for (int ww = 1; ww < 8; ww++) g = fmaxf(g, red[sr][ww]);
      gmax[m][r] = g;
    }
  __syncthreads();
#pragma unroll
  for (int m = 0; m < 2; m++)
#pragma unroll
    for (int r = 0; r < 4; r++) {
      float ssum = 0.f;
#pragma unroll
      for (int n = 0; n < 4; n++) {
        float e = __expf(acc[m][n][r] - gmax[m][r]);
        acc[m][n][r] = e;
        ssum += e;
      }
#pragma unroll
      for (int off = 1; off < 16; off <<= 1) ssum += __shfl_xor(ssum, off, 16);
      if ((l & 15) == 0) red[m * 16 + (l >> 4) * 4 + r][w] = ssum;
    }
  __syncthreads();
#pragma unroll
  for (int m = 0; m < 2; m++)
#pragma unroll
    for (int r = 0; r < 4; r++) {
      int sr = m * 16 + (l >> 4) * 4 + r;
      float tot = 0.f;
#pragma unroll
      for (int ww = 0; ww < 8; ww++) tot += red[sr][ww];
      float sc = 0.0625f / tot;
#pragma unroll
      for (int n = 0; n < 4; n++)
        P[(s0 + sr) * 512 + w * 64 + n * 16 + (l & 15)] = f2b(acc[m][n][r] * sc);
    }
}

// =====================================================================
// 6) PV products: out = P @ V  (V^T staged from actT)
// grid 256 x 512 : p=bx>>6, b=(bx>>4)&3, sblk=bx&15 (BM=32, N=256, K=512)
__global__ __launch_bounds__(512) void k_pv(const ushortT* __restrict__ P16,
                                            const ushortT* __restrict__ actT,
                                            float* __restrict__ pvv, float* __restrict__ pva,
                                            ushortT* __restrict__ vc16, ushortT* __restrict__ ac16) {
  __shared__ ushortT Al[4][32][8];
  __shared__ ushortT Bl[4][256][8];
  const int tid = threadIdx.x, l = tid & 63, w = tid >> 6;
  const int bx = blockIdx.x;
  const int p = bx >> 6, b = (bx >> 4) & 3, sblk = bx & 15;
  const int s0 = sblk * 32;
  const ushortT* A = P16 + p * 1048576 + b * 262144;      // [512][512]
  const int vsel = (p == 0) ? 0 : (p == 2) ? 1 : 2;       // img, aud, com
  const ushortT* VT = actT + vsel * ACT_E + b * 131072;   // [256][512]

  f32x4 acc[2][2] = {};
  ush8 ra, rb[2];
  int a_row = tid >> 2, a_seg = tid & 3;
  auto sload = [&](int t0) {
    if (tid < 128) ra = *(const ush8*)(A + (s0 + a_row) * 512 + t0 + a_seg * 8);
#pragma unroll
    for (int q = 0; q < 2; q++) {
      int slot = tid + q * 512;
      rb[q] = *(const ush8*)(VT + (slot >> 2) * 512 + t0 + (slot & 3) * 8);
    }
  };
  auto swrite = [&]() {
    if (tid < 128) *(ush8*)(&Al[a_seg][a_row][0]) = ra;
#pragma unroll
    for (int q = 0; q < 2; q++) {
      int slot = tid + q * 512;
      *(ush8*)(&Bl[slot & 3][slot >> 2][0]) = rb[q];
    }
  };

  sload(0); swrite(); __syncthreads();
  for (int s = 0; s < 16; s++) {
    if (s < 15) sload((s + 1) * 32);
    int ks = l >> 4;
    bf16x8 a[2], bb[2];
#pragma unroll
    for (int m = 0; m < 2; m++) a[m] = *(const bf16x8*)(&Al[ks][m * 16 + (l & 15)][0]);
#pragma unroll
    for (int n = 0; n < 2; n++) bb[n] = *(const bf16x8*)(&Bl[ks][w * 32 + n * 16 + (l & 15)][0]);
#pragma unroll
    for (int m = 0; m < 2; m++)
#pragma unroll
      for (int n = 0; n < 2; n++) acc[m][n] = MFMA16(a[m], bb[n], acc[m][n]);
    if (s == 15) break;
    __syncthreads();
    swrite();
    __syncthreads();
  }
#pragma unroll
  for (int m = 0; m < 2; m++)
#pragma unroll
    for (int n = 0; n < 2; n++)
#pragma unroll
      for (int r = 0; r < 4; r++) {
        int row = s0 + m * 16 + (l >> 4) * 4 + r;
        int col = w * 32 + n * 16 + (l & 15);
        int gi = (b * 512 + row) * 256 + col;
        float v = acc[m][n][r];
        if (p == 0) pvv[gi] = v;
        else if (p == 1) vc16[gi] = f2b(v);
        else if (p == 2) pva[gi] = v;
        else ac16[gi] = f2b(v);
      }
}

// =====================================================================
// 7) two linears + combine: cf = (1 + A@W1 + b1) * pv + (A@W2 + b2)
// grid 128 x 512 : side=bx>>6, sblk=bx&63 (BM=32, N=256, K=256)
__global__ __launch_bounds__(512) void k_lin4c(
    const ushortT* __restrict__ vc16, const ushortT* __restrict__ ac16,
    const ushortT* __restrict__ wT,
    const float* __restrict__ w5b, const float* __restrict__ w6b,
    const float* __restrict__ w7b, const float* __restrict__ w8b,
    const float* __restrict__ pvv, const float* __restrict__ pva,
    ushortT* __restrict__ cfv, ushortT* __restrict__ cfa) {
  __shared__ ushortT Al[4][32][8];
  __shared__ ushortT B1[4][256][8];
  __shared__ ushortT B2[4][256][8];
  const int tid = threadIdx.x, l = tid & 63, w = tid >> 6;
  const int bx = blockIdx.x;
  const int side = bx >> 6, sblk = bx & 63;
  const int s0 = sblk * 32;
  const ushortT* A = side ? ac16 : vc16;
  const ushortT* W1 = wT + (side ? 7 : 5) * WD_E;
  const ushortT* W2 = wT + (side ? 8 : 6) * WD_E;
  const float* bb1 = side ? w7b : w5b;
  const float* bb2 = side ? w8b : w6b;
  const float* pv = side ? pva : pvv;
  ushortT* out = side ? cfa : cfv;

  f32x4 acc1[2][2] = {}, acc2[2][2] = {};
  ush8 ra, rb1[2], rb2[2];
  int a_row = tid >> 2, a_seg = tid & 3;
  auto sload = [&](int k0) {
    if (tid < 128) ra = *(const ush8*)(A + (s0 + a_row) * 256 + k0 + a_seg * 8);
#pragma unroll
    for (int q = 0; q < 2; q++) {
      int slot = tid + q * 512;
      rb1[q] = *(const ush8*)(W1 + (slot >> 2) * 256 + k0 + (slot & 3) * 8);
      rb2[q] = *(const ush8*)(W2 + (slot >> 2) * 256 + k0 + (slot & 3) * 8);
    }
  };
  auto swrite = [&]() {
    if (tid < 128) *(ush8*)(&Al[a_seg][a_row][0]) = ra;
#pragma unroll
    for (int q = 0; q < 2; q++) {
      int slot = tid + q * 512;
      *(ush8*)(&B1[slot & 3][slot >> 2][0]) = rb1[q];
      *(ush8*)(&B2[slot & 3][slot >> 2][0]) = rb2[q];
    }
  };

  sload(0); swrite(); __syncthreads();
  for (int s = 0; s < 8; s++) {
    if (s < 7) sload((s + 1) * 32);
    int ks = l >> 4;
    bf16x8 a[2], x1[2], x2[2];
#pragma unroll
    for (int m = 0; m < 2; m++) a[m] = *(const bf16x8*)(&Al[ks][m * 16 + (l & 15)][0]);
#pragma unroll
    for (int n = 0; n < 2; n++) {
      x1[n] = *(const bf16x8*)(&B1[ks][w * 32 + n * 16 + (l & 15)][0]);
      x2[n] = *(const bf16x8*)(&B2[ks][w * 32 + n * 16 + (l & 15)][0]);
    }
#pragma unroll
    for (int m = 0; m < 2; m++)
#pragma unroll
      for (int n = 0; n < 2; n++) {
        acc1[m][n] = MFMA16(a[m], x1[n], acc1[m][n]);
        acc2[m][n] = MFMA16(a[m], x2[n], acc2[m][n]);
      }
    if (s == 7) break;
    __syncthreads();
    swrite();
    __syncthreads();
  }
#pragma unroll
  for (int m = 0; m < 2; m++)
#pragma unroll
    for (int n = 0; n < 2; n++)
#pragma unroll
      for (int r = 0; r < 4; r++) {
        int row = s0 + m * 16 + (l >> 4) * 4 + r;
        int col = w * 32 + n * 16 + (l & 15);
        int gi = row * 256 + col;
        float u1 = acc1[m][n][r] + bb1[col];
        float u2 = acc2[m][n][r] + bb2[col];
        out[gi] = f2b((1.f + u1) * pv[gi] + u2);
      }
}

// =====================================================================
// 8) bilinear: m32[bs,k] = sum_i cfv[bs,i] * (sum_j W[k,i,j] cfa[bs,j])
//            = rowsum( (cfa @ W[k]^T) .* cfv )
// grid 4096 x 512 : k=bx>>4, sblk=bx&15 (BM=128 rows, N=256 i, K=256 j)
__global__ __launch_bounds__(512) void k_bilinear(const ushortT* __restrict__ cfa,
                                                  const ushortT* __restrict__ cfv,
                                                  const ushortT* __restrict__ bil16,
                                                  float* __restrict__ m32) {
  __shared__ ushortT Al[4][128][8];
  __shared__ ushortT Bl[4][256][8];
  __shared__ float red[128][4];
  const int tid = threadIdx.x, l = tid & 63, w = tid >> 6;
  const int bx = blockIdx.x;
  const int k = bx >> 4, sblk = bx & 15;
  const int s0 = sblk * 128;
  const int wr = w >> 2, wc = w & 3;
  const ushortT* Wk = bil16 + k * 65536;   // [i][j] row-major, j contiguous

  f32x4 acc[4][4] = {};
  ush8 ra, rb[2];
  int a_row = tid >> 2, a_seg = tid & 3;
  auto sload = [&](int j0) {
    ra = *(const ush8*)(cfa + (s0 + a_row) * 256 + j0 + a_seg * 8);
#pragma unroll
    for (int q = 0; q < 2; q++) {
      int slot = tid + q * 512;
      rb[q] = *(const ush8*)(Wk + (slot >> 2) * 256 + j0 + (slot & 3) * 8);
    }
  };
  auto swrite = [&]() {
    *(ush8*)(&Al[a_seg][a_row][0]) = ra;
#pragma unroll
    for (int q = 0; q < 2; q++) {
      int slot = tid + q * 512;
      *(ush8*)(&Bl[slot & 3][slot >> 2][0]) = rb[q];
    }
  };

  sload(0); swrite(); __syncthreads();
  for (int s = 0; s < 8; s++) {
    if (s < 7) sload((s + 1) * 32);
    int ks = l >> 4;
    bf16x8 a[4], bb[4];
#pragma unroll
    for (int m = 0; m < 4; m++) a[m] = *(const bf16x8*)(&Al[ks][wr * 64 + m * 16 + (l & 15)][0]);
#pragma unroll
    for (int n = 0; n < 4; n++) bb[n] = *(const bf16x8*)(&Bl[ks][wc * 64 + n * 16 + (l & 15)][0]);
#pragma unroll
    for (int m = 0; m < 4; m++)
#pragma unroll
      for (int n = 0; n < 4; n++) acc[m][n] = MFMA16(a[m], bb[n], acc[m][n]);
    if (s == 7) break;
    __syncthreads();
    swrite();
    __syncthreads();
  }
  // epilogue: multiply by cfv, reduce over i
#pragma unroll
  for (int m = 0; m < 4; m++)
#pragma unroll
    for (int r = 0; r < 4; r++) {
      int row = wr * 64 + m * 16 + (l >> 4) * 4 + r;
      const ushortT* vrow = cfv + (s0 + row) * 256 + wc * 64;
      float ps = 0.f;
#pragma unroll
      for (int n = 0; n < 4; n++) ps += acc[m][n][r] * b2f(vrow[n * 16 + (l & 15)]);
#pragma unroll
      for (int off = 1; off < 16; off <<= 1) ps += __shfl_xor(ps, off, 16);
      if ((l & 15) == 0) red[row][wc] = ps;
    }
  __syncthreads();
  if (tid < 128) {
    float tot = red[tid][0] + red[tid][1] + red[tid][2] + red[tid][3];
    m32[(s0 + tid) * 256 + k] = tot;
  }
}

// =====================================================================
// 9) final gate: j = sigmoid(m); Z = t*j*img + (1-j)*aud; out0=Z+img; out1=Z+aud
// grid 512 x 256 (exactly 131072 float4)
__global__ void k_final(const float* __restrict__ m32, const float* __restrict__ img,
                        const float* __restrict__ aud, const float* __restrict__ t_o,
                        float* __restrict__ out0, float* __restrict__ out1) {
  int i = blockIdx.x * 256 + threadIdx.x;
  float t = t_o[0];
  float4 m = ((const float4*)m32)[i];
  float4 a = ((const float4*)img)[i];
  float4 u = ((const float4*)aud)[i];
  float4 o0, o1;
  {
    float j = 1.f / (1.f + __expf(-m.x)); float Z = t * j * a.x + (1.f - j) * u.x;
    o0.x = Z + a.x; o1.x = Z + u.x;
  }
  {
    float j = 1.f / (1.f + __expf(-m.y)); float Z = t * j * a.y + (1.f - j) * u.y;
    o0.y = Z + a.y; o1.y = Z + u.y;
  }
  {
    float j = 1.f / (1.f + __expf(-m.z)); float Z = t * j * a.z + (1.f - j) * u.z;
    o0.z = Z + a.z; o1.z = Z + u.z;
  }
  {
    float j = 1.f / (1.f + __expf(-m.w)); float Z = t * j * a.w + (1.f - j) * u.w;
    o0.w = Z + a.w; o1.w = Z + u.w;
  }
  ((float4*)out0)[i] = o0;
  ((float4*)out1)[i] = o1;
}

// =====================================================================
extern "C" void kernel_launch(void* const* d_in, const int* in_sizes, int n_in,
                              void* d_out, int out_size, void* d_ws, size_t ws_size,
                              hipStream_t stream) {
  const float* img   = (const float*)d_in[0];
  const float* aud   = (const float*)d_in[1];
  const float* com   = (const float*)d_in[2];
  const float* qv_w  = (const float*)d_in[3];
  const float* qv_b  = (const float*)d_in[4];
  const float* qa_w  = (const float*)d_in[5];
  const float* qa_b  = (const float*)d_in[6];
  const float* kv_w  = (const float*)d_in[7];
  const float* kv_b  = (const float*)d_in[8];
  const float* ka_w  = (const float*)d_in[9];
  const float* ka_b  = (const float*)d_in[10];
  const float* cc_w  = (const float*)d_in[11];
  const float* cc_b  = (const float*)d_in[12];
  const float* w5_w  = (const float*)d_in[13];
  const float* w5_b  = (const float*)d_in[14];
  const float* w6_w  = (const float*)d_in[15];
  const float* w6_b  = (const float*)d_in[16];
  const float* w7_w  = (const float*)d_in[17];
  const float* w7_b  = (const float*)d_in[18];
  const float* w8_w  = (const float*)d_in[19];
  const float* w8_b  = (const float*)d_in[20];
  const float* bil_w = (const float*)d_in[21];
  const float* t_o   = (const float*)d_in[22];
  float* out = (float*)d_out;

  char* ws = (char*)d_ws;
  ushortT* act16  = (ushortT*)(ws + OFF_ACT16);
  ushortT* actT16 = (ushortT*)(ws + OFF_ACTT16);
  ushortT* w16t   = (ushortT*)(ws + OFF_W16T);
  ushortT* proj16 = (ushortT*)(ws + OFF_PROJ16);
  ushortT* P16    = (ushortT*)(ws + OFF_P16);
  ushortT* vc16   = (ushortT*)(ws + OFF_VC16);
  ushortT* ac16   = (ushortT*)(ws + OFF_AC16);
  float*   pvv32  = (float*)(ws + OFF_PVV32);
  float*   pva32  = (float*)(ws + OFF_PVA32);
  ushortT* cfv16  = (ushortT*)(ws + OFF_CFV16);
  ushortT* cfa16  = (ushortT*)(ws + OFF_CFA16);
  float*   m32    = (float*)(ws + OFF_M32);
  ushortT* bil16  = (ushortT*)(ws + OFF_BIL16);

  k_cvt_acts<<<384, 256, 0, stream>>>(img, aud, com, act16);
  k_cvt_bil<<<2048, 256, 0, stream>>>(bil_w, bil16);
  k_transpose<<<528, 256, 0, stream>>>(img, aud, com, qv_w, qa_w, kv_w, ka_w, cc_w,
                                       w5_w, w6_w, w7_w, w8_w, actT16, w16t);
  k_linear5<<<320, 512, 0, stream>>>(act16, w16t, qv_b, qa_b, kv_b, ka_b, cc_b, proj16);
  k_attn<<<256, 512, 0, stream>>>(proj16, P16);
  k_pv<<<256, 512, 0, stream>>>(P16, actT16, pvv32, pva32, vc16, ac16);
  k_lin4c<<<128, 512, 0, stream>>>(vc16, ac16, w16t, w5_b, w6_b, w7_b, w8_b,
                                   pvv32, pva32, cfv16, cfa16);
  k_bilinear<<<4096, 512, 0, stream>>>(cfa16, cfv16, bil16, m32);
  k_final<<<512, 256, 0, stream>>>(m32, img, aud, t_o, out, out + 524288);
}

// Round 2
// 157.454 us; speedup vs baseline: 1.2683x; 1.2683x over previous
//
#include <hip/hip_runtime.h>
#include <hip/hip_bf16.h>

// ---------- types ----------
typedef unsigned short ushortT;
typedef __bf16 bf16x8 __attribute__((ext_vector_type(8)));
typedef float f32x4 __attribute__((ext_vector_type(4)));
typedef ushortT ush8 __attribute__((ext_vector_type(8)));
typedef ushortT ush4 __attribute__((ext_vector_type(4)));

#define MFMA16(a, b, c) __builtin_amdgcn_mfma_f32_16x16x32_bf16((a), (b), (c), 0, 0, 0)

__device__ __forceinline__ ushortT f2b(float f) {
  __hip_bfloat16 h = __float2bfloat16(f);
  return __builtin_bit_cast(ushortT, h);
}
__device__ __forceinline__ float b2f(ushortT u) {
  __hip_bfloat16 h = __builtin_bit_cast(__hip_bfloat16, u);
  return __bfloat162float(h);
}

// async global->LDS, 16B per lane
__device__ __forceinline__ void async16(const void* g, void* l) {
  __builtin_amdgcn_global_load_lds((const __attribute__((address_space(1))) unsigned int*)g,
                                   (__attribute__((address_space(3))) unsigned int*)l, 16, 0, 0);
}

// ---------- problem dims ----------
// B=4, S=512, D=256, ROWS = B*S = 2048
#define ACT_E 524288   // 2048*256 elements
#define WD_E  65536    // 256*256

// ---------- ws layout (bytes) ----------
// transient zone [0, ~27.4MB): act16/actT16/w16t/proj16/P16/vc/ac/pvv/pva
// PART (33.5MB) overlaps the transient zone (all dead when bilinear runs).
#define OFF_ACT16   0u          // 3 * ACT_E * 2 = 3145728
#define OFF_ACTT16  3145728u    // 3 * ACT_E * 2
#define OFF_W16T    6291456u    // 9 * WD_E * 2 = 1179648
#define OFF_PROJ16  7471104u    // 5 * ACT_E * 2 = 5242880
#define OFF_P16     12713984u   // 4 * 1048576 * 2 = 8388608
#define OFF_VC16    21102592u   // ACT_E*2
#define OFF_AC16    22151168u
#define OFF_PVV32   23199744u   // ACT_E*4
#define OFF_PVA32   25296896u   // ends 27394048
#define OFF_PART    0u          // 16 * 2048*256*4 = 33554432 (overlaps transients)
#define OFF_BIL16   33554432u   // 16777216*2 = 33554432, ends 67108864
#define OFF_CFV16   67108864u   // ACT_E*2
#define OFF_CFA16   68157440u   // ends 69206016

// =====================================================================
// 1) convert img/audio/common fp32 -> bf16 (same layout)
__global__ void k_cvt_acts(const float* __restrict__ img, const float* __restrict__ aud,
                           const float* __restrict__ com, ushortT* __restrict__ dst) {
  int i4 = blockIdx.x * 256 + threadIdx.x;
#pragma unroll
  for (int q = 0; q < 4; q++) {
    int idx4 = i4 + q * 98304;
    int flat = idx4 * 4;
    const float* src;
    int off;
    if (flat < 524288)        { src = img; off = flat; }
    else if (flat < 1048576)  { src = aud; off = flat - 524288; }
    else                      { src = com; off = flat - 1048576; }
    float4 v = *(const float4*)(src + off);
    ush4 u = { f2b(v.x), f2b(v.y), f2b(v.z), f2b(v.w) };
    *(ush4*)(dst + idx4 * 4) = u;
  }
}

// 2) convert bil_w fp32 -> bf16
__global__ void k_cvt_bil(const float* __restrict__ bil, ushortT* __restrict__ dst) {
  int i4 = blockIdx.x * 256 + threadIdx.x;
#pragma unroll
  for (int q = 0; q < 8; q++) {
    int idx4 = i4 + q * 524288;
    float4 v = *(const float4*)(bil + idx4 * 4);
    ush4 u = { f2b(v.x), f2b(v.y), f2b(v.z), f2b(v.w) };
    *(ush4*)(dst + idx4 * 4) = u;
  }
}

// 3) transpose+convert
__global__ void k_transpose(const float* __restrict__ img, const float* __restrict__ aud,
                            const float* __restrict__ com,
                            const float* w0, const float* w1, const float* w2,
                            const float* w3, const float* w4, const float* w5,
                            const float* w6, const float* w7, const float* w8,
                            ushortT* __restrict__ actT, ushortT* __restrict__ wT) {
  __shared__ ushortT tl[64][72];
  int tid = threadIdx.x;
  int bx = blockIdx.x;
  const float* src;
  ushortT* dst;
  int R, C, r0, c0;
  if (bx < 384) {
    int inst = bx >> 5, tile = bx & 31;
    int act = inst >> 2, bb = inst & 3;
    src = (act == 0 ? img : (act == 1 ? aud : com)) + bb * 131072;
    dst = actT + act * 524288 + bb * 131072;
    R = 512; C = 256;
    r0 = (tile >> 2) * 64; c0 = (tile & 3) * 64;
  } else {
    int bw = bx - 384;
    int w = bw >> 4, tile = bw & 15;
    const float* s;
    switch (w) {
      case 0: s = w0; break; case 1: s = w1; break; case 2: s = w2; break;
      case 3: s = w3; break; case 4: s = w4; break; case 5: s = w5; break;
      case 6: s = w6; break; case 7: s = w7; break; default: s = w8; break;
    }
    src = s;
    dst = wT + w * 65536;
    R = 256; C = 256;
    r0 = (tile >> 2) * 64; c0 = (tile & 3) * 64;
  }
#pragma unroll
  for (int q = 0; q < 4; q++) {
    int rr = q * 16 + (tid >> 4);
    int cs = (tid & 15) * 4;
    float4 v = *(const float4*)(src + (r0 + rr) * C + c0 + cs);
    tl[rr][cs + 0] = f2b(v.x);
    tl[rr][cs + 1] = f2b(v.y);
    tl[rr][cs + 2] = f2b(v.z);
    tl[rr][cs + 3] = f2b(v.w);
  }
  __syncthreads();
#pragma unroll
  for (int q = 0; q < 4; q++) {
    int cc = q * 16 + (tid >> 4);
    int rs = (tid & 15) * 4;
    ush4 u = { tl[rs + 0][cc], tl[rs + 1][cc], tl[rs + 2][cc], tl[rs + 3][cc] };
    *(ush4*)(dst + (c0 + cc) * R + r0 + rs) = u;
  }
}

// =====================================================================
// 4) five input linears
__global__ __launch_bounds__(512) void k_linear5(
    const ushortT* __restrict__ act16, const ushortT* __restrict__ wT,
    const float* __restrict__ b0, const float* __restrict__ b1,
    const float* __restrict__ b2, const float* __restrict__ b3,
    const float* __restrict__ b4, ushortT* __restrict__ proj16) {
  __shared__ ushortT Al[4][32][8];
  __shared__ ushortT Bl[4][256][8];
  const int tid = threadIdx.x, l = tid & 63, w = tid >> 6;
  const int bx = blockIdx.x;
  const int op = bx >> 6, sblk = bx & 63;
  const int s0 = sblk * 32;
  const int xsel = (op == 4) ? 2 : (op & 1);
  const ushortT* X = act16 + xsel * ACT_E;
  const ushortT* W = wT + op * WD_E;
  const float* bias = op == 0 ? b0 : op == 1 ? b1 : op == 2 ? b2 : op == 3 ? b3 : b4;
  ushortT* out = proj16 + op * ACT_E;

  f32x4 acc[2][2] = {};
  ush8 ra, rb[2];
  int a_row = tid >> 2, a_seg = tid & 3;

  auto sload = [&](int k0) {
    if (tid < 128) ra = *(const ush8*)(X + (s0 + a_row) * 256 + k0 + a_seg * 8);
#pragma unroll
    for (int q = 0; q < 2; q++) {
      int slot = tid + q * 512;
      rb[q] = *(const ush8*)(W + (slot >> 2) * 256 + k0 + (slot & 3) * 8);
    }
  };
  auto swrite = [&]() {
    if (tid < 128) *(ush8*)(&Al[a_seg][a_row][0]) = ra;
#pragma unroll
    for (int q = 0; q < 2; q++) {
      int slot = tid + q * 512;
      *(ush8*)(&Bl[slot & 3][slot >> 2][0]) = rb[q];
    }
  };

  sload(0); swrite(); __syncthreads();
  for (int s = 0; s < 8; s++) {
    if (s < 7) sload((s + 1) * 32);
    int ks = l >> 4;
    bf16x8 a[2], bb[2];
#pragma unroll
    for (int m = 0; m < 2; m++) a[m] = *(const bf16x8*)(&Al[ks][m * 16 + (l & 15)][0]);
#pragma unroll
    for (int n = 0; n < 2; n++) bb[n] = *(const bf16x8*)(&Bl[ks][w * 32 + n * 16 + (l & 15)][0]);
#pragma unroll
    for (int m = 0; m < 2; m++)
#pragma unroll
      for (int n = 0; n < 2; n++) acc[m][n] = MFMA16(a[m], bb[n], acc[m][n]);
    if (s == 7) break;
    __syncthreads();
    swrite();
    __syncthreads();
  }
#pragma unroll
  for (int m = 0; m < 2; m++)
#pragma unroll
    for (int n = 0; n < 2; n++)
#pragma unroll
      for (int r = 0; r < 4; r++) {
        int row = s0 + m * 16 + (l >> 4) * 4 + r;
        int col = w * 32 + n * 16 + (l & 15);
        out[row * 256 + col] = f2b(acc[m][n][r] + bias[col]);
      }
}

// =====================================================================
// 5) attention: P = softmax(Q K^T) * (1/16)
__global__ __launch_bounds__(512) void k_attn(const ushortT* __restrict__ proj16,
                                              ushortT* __restrict__ P16) {
  __shared__ ushortT Ql[8][4][32][8];
  __shared__ ushortT Kl[4][512][8];
  __shared__ float red[32][8];
  const int tid = threadIdx.x, l = tid & 63, w = tid >> 6;
  const int bx = blockIdx.x;
  const int p = bx >> 6, b = (bx >> 4) & 3, sblk = bx & 15;
  const int s0 = sblk * 32;
  const int qsel = (p < 2) ? 0 : 1;
  const int ksel = (p == 0) ? 2 : (p == 2) ? 3 : 4;
  const ushortT* Q = proj16 + qsel * ACT_E + b * 131072;
  const ushortT* K = proj16 + ksel * ACT_E + b * 131072;
  ushortT* P = P16 + p * 1048576 + b * 262144;

#pragma unroll
  for (int q = 0; q < 2; q++) {
    int slot = tid + q * 512;
    int row = slot >> 5, seg = slot & 31;
    ush8 v = *(const ush8*)(Q + (s0 + row) * 256 + seg * 8);
    *(ush8*)(&Ql[seg >> 2][seg & 3][row][0]) = v;
  }

  f32x4 acc[2][4] = {};
  ush8 rk[4];
  auto kload = [&](int d0) {
#pragma unroll
    for (int q = 0; q < 4; q++) {
      int slot = tid + q * 512;
      rk[q] = *(const ush8*)(K + (slot >> 2) * 256 + d0 + (slot & 3) * 8);
    }
  };
  auto kwrite = [&]() {
#pragma unroll
    for (int q = 0; q < 4; q++) {
      int slot = tid + q * 512;
      *(ush8*)(&Kl[slot & 3][slot >> 2][0]) = rk[q];
    }
  };

  kload(0); kwrite(); __syncthreads();
  for (int s = 0; s < 8; s++) {
    if (s < 7) kload((s + 1) * 32);
    int ks = l >> 4;
    bf16x8 a[2], bb[4];
#pragma unroll
    for (int m = 0; m < 2; m++) a[m] = *(const bf16x8*)(&Ql[s][ks][m * 16 + (l & 15)][0]);
#pragma unroll
    for (int n = 0; n < 4; n++) bb[n] = *(const bf16x8*)(&Kl[ks][w * 64 + n * 16 + (l & 15)][0]);
#pragma unroll
    for (int m = 0; m < 2; m++)
#pragma unroll
      for (int n = 0; n < 4; n++) acc[m][n] = MFMA16(a[m], bb[n], acc[m][n]);
    if (s == 7) break;
    __syncthreads();
    kwrite();
    __syncthreads();
  }

  float gmax[2][4];
#pragma unroll
  for (int m = 0; m < 2; m++)
#pragma unroll
    for (int r = 0; r < 4; r++) {
      float v = fmaxf(fmaxf(acc[m][0][r], acc[m][1][r]), fmaxf(acc[m][2][r], acc[m][3][r]));
#pragma unroll
      for (int off = 1; off < 16; off <<= 1) v = fmaxf(v, __shfl_xor(v, off, 16));
      if ((l & 15) == 0) red[m * 16 + (l >> 4) * 4 + r][w] = v;
    }
  __syncthreads();
#pragma unroll
  for (int m = 0; m < 2; m++)
#pragma unroll
    for (int r = 0; r < 4; r++) {
      int sr = m * 16 + (l >> 4) * 4 + r;
      float g = red[sr][0];
#pragma unroll
      for (int ww = 1; ww < 8; ww++) g = fmaxf(g, red[sr][ww]);
      gmax[m][r] = g;
    }
  __syncthreads();
#pragma unroll
  for (int m = 0; m < 2; m++)
#pragma unroll
    for (int r = 0; r < 4; r++) {
      float ssum = 0.f;
#pragma unroll
      for (int n = 0; n < 4; n++) {
        float e = __expf(acc[m][n][r] - gmax[m][r]);
        acc[m][n][r] = e;
        ssum += e;
      }
#pragma unroll
      for (int off = 1; off < 16; off <<= 1) ssum += __shfl_xor(ssum, off, 16);
      if ((l & 15) == 0) red[m * 16 + (l >> 4) * 4 + r][w] = ssum;
    }
  __syncthreads();
#pragma unroll
  for (int m = 0; m < 2; m++)
#pragma unroll
    for (int r = 0; r < 4; r++) {
      int sr = m * 16 + (l >> 4) * 4 + r;
      float tot = 0.f;
#pragma unroll
      for (int ww = 0; ww < 8; ww++) tot += red[sr][ww];
      float sc = 0.0625f / tot;
#pragma unroll
      for (int n = 0; n < 4; n++)
        P[(s0 + sr) * 512 + w * 64 + n * 16 + (l & 15)] = f2b(acc[m][n][r] * sc);
    }
}

// =====================================================================
// 6) PV products
__global__ __launch_bounds__(512) void k_pv(const ushortT* __restrict__ P16,
                                            const ushortT* __restrict__ actT,
                                            float* __restrict__ pvv, float* __restrict__ pva,
                                            ushortT* __restrict__ vc16, ushortT* __restrict__ ac16) {
  __shared__ ushortT Al[4][32][8];
  __shared__ ushortT Bl[4][256][8];
  const int tid = threadIdx.x, l = tid & 63, w = tid >> 6;
  const int bx = blockIdx.x;
  const int p = bx >> 6, b = (bx >> 4) & 3, sblk = bx & 15;
  const int s0 = sblk * 32;
  const ushortT* A = P16 + p * 1048576 + b * 262144;
  const int vsel = (p == 0) ? 0 : (p == 2) ? 1 : 2;
  const ushortT* VT = actT + vsel * ACT_E + b * 131072;

  f32x4 acc[2][2] = {};
  ush8 ra, rb[2];
  int a_row = tid >> 2, a_seg = tid & 3;
  auto sload = [&](int t0) {
    if (tid < 128) ra = *(const ush8*)(A + (s0 + a_row) * 512 + t0 + a_seg * 8);
#pragma unroll
    for (int q = 0; q < 2; q++) {
      int slot = tid + q * 512;
      rb[q] = *(const ush8*)(VT + (slot >> 2) * 512 + t0 + (slot & 3) * 8);
    }
  };
  auto swrite = [&]() {
    if (tid < 128) *(ush8*)(&Al[a_seg][a_row][0]) = ra;
#pragma unroll
    for (int q = 0; q < 2; q++) {
      int slot = tid + q * 512;
      *(ush8*)(&Bl[slot & 3][slot >> 2][0]) = rb[q];
    }
  };

  sload(0); swrite(); __syncthreads();
  for (int s = 0; s < 16; s++) {
    if (s < 15) sload((s + 1) * 32);
    int ks = l >> 4;
    bf16x8 a[2], bb[2];
#pragma unroll
    for (int m = 0; m < 2; m++) a[m] = *(const bf16x8*)(&Al[ks][m * 16 + (l & 15)][0]);
#pragma unroll
    for (int n = 0; n < 2; n++) bb[n] = *(const bf16x8*)(&Bl[ks][w * 32 + n * 16 + (l & 15)][0]);
#pragma unroll
    for (int m = 0; m < 2; m++)
#pragma unroll
      for (int n = 0; n < 2; n++) acc[m][n] = MFMA16(a[m], bb[n], acc[m][n]);
    if (s == 15) break;
    __syncthreads();
    swrite();
    __syncthreads();
  }
#pragma unroll
  for (int m = 0; m < 2; m++)
#pragma unroll
    for (int n = 0; n < 2; n++)
#pragma unroll
      for (int r = 0; r < 4; r++) {
        int row = s0 + m * 16 + (l >> 4) * 4 + r;
        int col = w * 32 + n * 16 + (l & 15);
        int gi = (b * 512 + row) * 256 + col;
        float v = acc[m][n][r];
        if (p == 0) pvv[gi] = v;
        else if (p == 1) vc16[gi] = f2b(v);
        else if (p == 2) pva[gi] = v;
        else ac16[gi] = f2b(v);
      }
}

// =====================================================================
// 7) two linears + combine
__global__ __launch_bounds__(512) void k_lin4c(
    const ushortT* __restrict__ vc16, const ushortT* __restrict__ ac16,
    const ushortT* __restrict__ wT,
    const float* __restrict__ w5b, const float* __restrict__ w6b,
    const float* __restrict__ w7b, const float* __restrict__ w8b,
    const float* __restrict__ pvv, const float* __restrict__ pva,
    ushortT* __restrict__ cfv, ushortT* __restrict__ cfa) {
  __shared__ ushortT Al[4][32][8];
  __shared__ ushortT B1[4][256][8];
  __shared__ ushortT B2[4][256][8];
  const int tid = threadIdx.x, l = tid & 63, w = tid >> 6;
  const int bx = blockIdx.x;
  const int side = bx >> 6, sblk = bx & 63;
  const int s0 = sblk * 32;
  const ushortT* A = side ? ac16 : vc16;
  const ushortT* W1 = wT + (side ? 7 : 5) * WD_E;
  const ushortT* W2 = wT + (side ? 8 : 6) * WD_E;
  const float* bb1 = side ? w7b : w5b;
  const float* bb2 = side ? w8b : w6b;
  const float* pv = side ? pva : pvv;
  ushortT* out = side ? cfa : cfv;

  f32x4 acc1[2][2] = {}, acc2[2][2] = {};
  ush8 ra, rb1[2], rb2[2];
  int a_row = tid >> 2, a_seg = tid & 3;
  auto sload = [&](int k0) {
    if (tid < 128) ra = *(const ush8*)(A + (s0 + a_row) * 256 + k0 + a_seg * 8);
#pragma unroll
    for (int q = 0; q < 2; q++) {
      int slot = tid + q * 512;
      rb1[q] = *(const ush8*)(W1 + (slot >> 2) * 256 + k0 + (slot & 3) * 8);
      rb2[q] = *(const ush8*)(W2 + (slot >> 2) * 256 + k0 + (slot & 3) * 8);
    }
  };
  auto swrite = [&]() {
    if (tid < 128) *(ush8*)(&Al[a_seg][a_row][0]) = ra;
#pragma unroll
    for (int q = 0; q < 2; q++) {
      int slot = tid + q * 512;
      *(ush8*)(&B1[slot & 3][slot >> 2][0]) = rb1[q];
      *(ush8*)(&B2[slot & 3][slot >> 2][0]) = rb2[q];
    }
  };

  sload(0); swrite(); __syncthreads();
  for (int s = 0; s < 8; s++) {
    if (s < 7) sload((s + 1) * 32);
    int ks = l >> 4;
    bf16x8 a[2], x1[2], x2[2];
#pragma unroll
    for (int m = 0; m < 2; m++) a[m] = *(const bf16x8*)(&Al[ks][m * 16 + (l & 15)][0]);
#pragma unroll
    for (int n = 0; n < 2; n++) {
      x1[n] = *(const bf16x8*)(&B1[ks][w * 32 + n * 16 + (l & 15)][0]);
      x2[n] = *(const bf16x8*)(&B2[ks][w * 32 + n * 16 + (l & 15)][0]);
    }
#pragma unroll
    for (int m = 0; m < 2; m++)
#pragma unroll
      for (int n = 0; n < 2; n++) {
        acc1[m][n] = MFMA16(a[m], x1[n], acc1[m][n]);
        acc2[m][n] = MFMA16(a[m], x2[n], acc2[m][n]);
      }
    if (s == 7) break;
    __syncthreads();
    swrite();
    __syncthreads();
  }
#pragma unroll
  for (int m = 0; m < 2; m++)
#pragma unroll
    for (int n = 0; n < 2; n++)
#pragma unroll
      for (int r = 0; r < 4; r++) {
        int row = s0 + m * 16 + (l >> 4) * 4 + r;
        int col = w * 32 + n * 16 + (l & 15);
        int gi = row * 256 + col;
        float u1 = acc1[m][n][r] + bb1[col];
        float u2 = acc2[m][n][r] + bb2[col];
        out[gi] = f2b((1.f + u1) * pv[gi] + u2);
      }
}

// =====================================================================
// 8) bilinear v2: one deep GEMM with i-fold.
// m[r,ko] = sum_i cfv[r,i] * ( sum_j cfa[r,j] * W[ko, i*256+j] )
// grid 256 = ic(16) x mb(8) x nb(2).  Block tile 256 rows x 128 ko.
// K-loop: 128 steps (16 i x 8 jsteps of BK=32). 3-buffer pipeline,
// counted vmcnt(3), one barrier/step, global_load_lds staging with
// XOR-swizzled addressing (conflict-free b128 fragment reads).
__global__ __launch_bounds__(512, 2) void k_bilinear2(
    const ushortT* __restrict__ cfa, const ushortT* __restrict__ cfv,
    const ushortT* __restrict__ W, float* __restrict__ part) {
  // LDS arena: A 3x16384 @0, B 3x8192 @49152, cfv f32 [256][16] @73728
  __shared__ char arena[90112];
  const int tid = threadIdx.x, l = tid & 63, w = tid >> 6;
  const int bx = blockIdx.x;
  const int ic = bx >> 4;
  const int mb = (bx >> 1) & 7;
  const int nb = bx & 1;
  const int r0 = mb * 256;
  const int ko0 = nb * 128;
  const int wr = w >> 1, wc = w & 1;   // 4 x 2 waves; wave tile 64 x 64

  // ---- cfv slice -> LDS fp32 [256][16]
  float* cfvl = (float*)(arena + 73728);
  {
    int row = tid >> 1, seg = tid & 1;
    ush8 v = *(const ush8*)(cfv + (r0 + row) * 256 + ic * 16 + seg * 8);
    float* d = cfvl + row * 16 + seg * 8;
#pragma unroll
    for (int q = 0; q < 8; q++) d[q] = b2f(v[q]);
  }

  // ---- staging geometry: phys slot -> logical (row,seg) via XOR involution
  int aP0 = tid * 16, aP1 = (tid + 512) * 16, bP = tid * 16;
  int aL0 = aP0 ^ (((aP0 >> 7) & 7) << 4);
  int aL1 = aP1 ^ (((aP1 >> 7) & 7) << 4);
  int bL  = bP  ^ (((bP  >> 7) & 7) << 4);
  const ushortT* gA0 = cfa + (r0 + (aL0 >> 6)) * 256 + ((aL0 >> 4) & 3) * 8;
  const ushortT* gA1 = cfa + (r0 + (aL1 >> 6)) * 256 + ((aL1 >> 4) & 3) * 8;
  const ushortT* gB  = W + (ko0 + (bL >> 6)) * 65536 + ic * 4096 + ((bL >> 4) & 3) * 8;

  auto stage = [&](int t, int bi) {
    char* Ab = arena + bi * 16384;
    char* Bb = arena + 49152 + bi * 8192;
    int js = (t & 7) * 32;
    async16(gA0 + js, Ab + aP0);
    async16(gA1 + js, Ab + aP1 - 8192 * 16 / 16);  // placeholder fixed below
    async16(gB + t * 32, Bb + bP);
  };
  // NOTE: aP1 is a byte offset into the A tile (8192..16383); use directly.

  // fragment read offsets (swizzled byte offsets within a tile)
  int aoff[4], boff[4];
#pragma unroll
  for (int m = 0; m < 4; m++) {
    int row = wr * 64 + m * 16 + (l & 15);
    int byte = row * 64 + (l >> 4) * 16;
    aoff[m] = byte ^ (((byte >> 7) & 7) << 4);
  }
#pragma unroll
  for (int n = 0; n < 4; n++) {
    int row = wc * 64 + n * 16 + (l & 15);
    int byte = row * 64 + (l >> 4) * 16;
    boff[n] = byte ^ (((byte >> 7) & 7) << 4);
  }

  f32x4 macc[4][4] = {};
  f32x4 acci[4][4] = {};

  // prologue: stage t=0 -> buf0, t=1 -> buf1
  {
    char* Ab = arena;  char* Bb = arena + 49152;
    async16(gA0 + 0, Ab + aP0);
    async16(gA1 + 0, Ab + aP1);
    async16(gB + 0, Bb + bP);
    Ab = arena + 16384; Bb = arena + 49152 + 8192;
    async16(gA0 + 32, Ab + aP0);
    async16(gA1 + 32, Ab + aP1);
    async16(gB + 32, Bb + bP);
  }

  int bi = 0;
  for (int t = 0; t < 128; t++) {
    if (t < 127) asm volatile("s_waitcnt vmcnt(3)" ::: "memory");
    else         asm volatile("s_waitcnt vmcnt(0)" ::: "memory");
    __builtin_amdgcn_s_barrier();

    char* Ab = arena + bi * 16384;
    char* Bb = arena + 49152 + bi * 8192;
    bf16x8 af[4], bf[4];
#pragma unroll
    for (int m = 0; m < 4; m++) af[m] = *(const bf16x8*)(Ab + aoff[m]);
#pragma unroll
    for (int n = 0; n < 4; n++) bf[n] = *(const bf16x8*)(Bb + boff[n]);
#pragma unroll
    for (int m = 0; m < 4; m++)
#pragma unroll
      for (int n = 0; n < 4; n++) acci[m][n] = MFMA16(af[m], bf[n], acci[m][n]);

    if ((t & 7) == 7) {
      int il = t >> 3;
#pragma unroll
      for (int m = 0; m < 4; m++) {
        int rbase = wr * 64 + m * 16 + ((l >> 4) << 2);
        float c0 = cfvl[(rbase + 0) * 16 + il];
        float c1 = cfvl[(rbase + 1) * 16 + il];
        float c2 = cfvl[(rbase + 2) * 16 + il];
        float c3 = cfvl[(rbase + 3) * 16 + il];
#pragma unroll
        for (int n = 0; n < 4; n++) {
          macc[m][n][0] += c0 * acci[m][n][0];
          macc[m][n][1] += c1 * acci[m][n][1];
          macc[m][n][2] += c2 * acci[m][n][2];
          macc[m][n][3] += c3 * acci[m][n][3];
          acci[m][n] = (f32x4){0.f, 0.f, 0.f, 0.f};
        }
      }
    }

    if (t + 2 < 128) {
      int nb3 = bi + 2; if (nb3 >= 3) nb3 -= 3;
      char* An = arena + nb3 * 16384;
      char* Bn = arena + 49152 + nb3 * 8192;
      int ts = t + 2;
      int js = (ts & 7) * 32;
      async16(gA0 + js, An + aP0);
      async16(gA1 + js, An + aP1);
      async16(gB + ts * 32, Bn + bP);
    }
    bi = (bi == 2) ? 0 : bi + 1;
  }

  // epilogue: store fp32 partial
  float* dst = part + ic * 524288 + r0 * 256 + ko0;
#pragma unroll
  for (int m = 0; m < 4; m++)
#pragma unroll
    for (int n = 0; n < 4; n++)
#pragma unroll
      for (int r = 0; r < 4; r++)
        dst[(wr * 64 + m * 16 + ((l >> 4) << 2) + r) * 256 + wc * 64 + n * 16 + (l & 15)] =
            macc[m][n][r];
}

// =====================================================================
// 9) final gate + partial reduction over 16 ic-chunks
__global__ void k_final2(const float* __restrict__ part, const float* __restrict__ img,
                         const float* __restrict__ aud, const float* __restrict__ t_o,
                         float* __restrict__ out0, float* __restrict__ out1) {
  int i = blockIdx.x * 256 + threadIdx.x;
  float t = t_o[0];
  float4 m = {0.f, 0.f, 0.f, 0.f};
#pragma unroll
  for (int ic = 0; ic < 16; ic++) {
    float4 p = ((const float4*)(part + ic * 524288))[i];
    m.x += p.x; m.y += p.y; m.z += p.z; m.w += p.w;
  }
  float4 a = ((const float4*)img)[i];
  float4 u = ((const float4*)aud)[i];
  float4 o0, o1;
  {
    float j = 1.f / (1.f + __expf(-m.x)); float Z = t * j * a.x + (1.f - j) * u.x;
    o0.x = Z + a.x; o1.x = Z + u.x;
  }
  {
    float j = 1.f / (1.f + __expf(-m.y)); float Z = t * j * a.y + (1.f - j) * u.y;
    o0.y = Z + a.y; o1.y = Z + u.y;
  }
  {
    float j = 1.f / (1.f + __expf(-m.z)); float Z = t * j * a.z + (1.f - j) * u.z;
    o0.z = Z + a.z; o1.z = Z + u.z;
  }
  {
    float j = 1.f / (1.f + __expf(-m.w)); float Z = t * j * a.w + (1.f - j) * u.w;
    o0.w = Z + a.w; o1.w = Z + u.w;
  }
  ((float4*)out0)[i] = o0;
  ((float4*)out1)[i] = o1;
}

// =====================================================================
extern "C" void kernel_launch(void* const* d_in, const int* in_sizes, int n_in,
                              void* d_out, int out_size, void* d_ws, size_t ws_size,
                              hipStream_t stream) {
  const float* img   = (const float*)d_in[0];
  const float* aud   = (const float*)d_in[1];
  const float* com   = (const float*)d_in[2];
  const float* qv_w  = (const float*)d_in[3];
  const float* qv_b  = (const float*)d_in[4];
  const float* qa_w  = (const float*)d_in[5];
  const float* qa_b  = (const float*)d_in[6];
  const float* kv_w  = (const float*)d_in[7];
  const float* kv_b  = (const float*)d_in[8];
  const float* ka_w  = (const float*)d_in[9];
  const float* ka_b  = (const float*)d_in[10];
  const float* cc_w  = (const float*)d_in[11];
  const float* cc_b  = (const float*)d_in[12];
  const float* w5_w  = (const float*)d_in[13];
  const float* w5_b  = (const float*)d_in[14];
  const float* w6_w  = (const float*)d_in[15];
  const float* w6_b  = (const float*)d_in[16];
  const float* w7_w  = (const float*)d_in[17];
  const float* w7_b  = (const float*)d_in[18];
  const float* w8_w  = (const float*)d_in[19];
  const float* w8_b  = (const float*)d_in[20];
  const float* bil_w = (const float*)d_in[21];
  const float* t_o   = (const float*)d_in[22];
  float* out = (float*)d_out;

  char* ws = (char*)d_ws;
  ushortT* act16  = (ushortT*)(ws + OFF_ACT16);
  ushortT* actT16 = (ushortT*)(ws + OFF_ACTT16);
  ushortT* w16t   = (ushortT*)(ws + OFF_W16T);
  ushortT* proj16 = (ushortT*)(ws + OFF_PROJ16);
  ushortT* P16    = (ushortT*)(ws + OFF_P16);
  ushortT* vc16   = (ushortT*)(ws + OFF_VC16);
  ushortT* ac16   = (ushortT*)(ws + OFF_AC16);
  float*   pvv32  = (float*)(ws + OFF_PVV32);
  float*   pva32  = (float*)(ws + OFF_PVA32);
  float*   part   = (float*)(ws + OFF_PART);
  ushortT* bil16  = (ushortT*)(ws + OFF_BIL16);
  ushortT* cfv16  = (ushortT*)(ws + OFF_CFV16);
  ushortT* cfa16  = (ushortT*)(ws + OFF_CFA16);

  k_cvt_acts<<<384, 256, 0, stream>>>(img, aud, com, act16);
  k_cvt_bil<<<2048, 256, 0, stream>>>(bil_w, bil16);
  k_transpose<<<528, 256, 0, stream>>>(img, aud, com, qv_w, qa_w, kv_w, ka_w, cc_w,
                                       w5_w, w6_w, w7_w, w8_w, actT16, w16t);
  k_linear5<<<320, 512, 0, stream>>>(act16, w16t, qv_b, qa_b, kv_b, ka_b, cc_b, proj16);
  k_attn<<<256, 512, 0, stream>>>(proj16, P16);
  k_pv<<<256, 512, 0, stream>>>(P16, actT16, pvv32, pva32, vc16, ac16);
  k_lin4c<<<128, 512, 0, stream>>>(vc16, ac16, w16t, w5_b, w6_b, w7_b, w8_b,
                                   pvv32, pva32, cfv16, cfa16);
  k_bilinear2<<<256, 512, 0, stream>>>(cfa16, cfv16, bil16, part);
  k_final2<<<512, 256, 0, stream>>>(part, img, aud, t_o, out, out + 524288);
}